// Round 1
// baseline (1160.379 us; speedup 1.0000x reference)
//
#include <hip/hip_runtime.h>

#define D 128
#define KN 32
#define WPAD 132  // padded LDS row stride (words) for transposed weights: bank stride 4, float4-aligned

__device__ __forceinline__ void fma4(float4& a, float s, const float4& b) {
  a.x = fmaf(s, b.x, a.x);
  a.y = fmaf(s, b.y, a.y);
  a.z = fmaf(s, b.z, a.z);
  a.w = fmaf(s, b.w, a.w);
}

// base[n,e] = sum_d x[n,d]*Wx[e,d] + bx[e] + bn[e] + bw[e]  -> written to d_out
__global__ __launch_bounds__(256) void base_kernel(
    const float* __restrict__ x, const float* __restrict__ Wx,
    const float* __restrict__ bx, const float* __restrict__ bn,
    const float* __restrict__ bw, float* __restrict__ out, int N)
{
  __shared__ float wxT[D * WPAD];   // wxT[d*WPAD + e] = Wx[e,d]
  __shared__ float xt[32 * D];      // 32 rows of x
  __shared__ float bias[D];
  const int tid = threadIdx.x;

  for (int i = tid; i < D * D; i += 256) {
    wxT[(i & (D - 1)) * WPAD + (i >> 7)] = Wx[i];
  }
  if (tid < D) bias[tid] = bx[tid] + bn[tid] + bw[tid];
  __syncthreads();

  const int eg = tid & 31, rg = tid >> 5;
  const int e0 = eg * 4;
  const int ntiles = (N + 31) >> 5;

  for (int tile = blockIdx.x; tile < ntiles; tile += gridDim.x) {
    const int r0 = tile * 32;
    for (int i = tid; i < 32 * D; i += 256) {
      const int r = r0 + (i >> 7);
      xt[i] = (r < N) ? x[(size_t)r * D + (i & (D - 1))] : 0.0f;
    }
    __syncthreads();

    float4 acc[4];
    #pragma unroll
    for (int ri = 0; ri < 4; ++ri) { acc[ri].x = acc[ri].y = acc[ri].z = acc[ri].w = 0.0f; }

    for (int d0 = 0; d0 < D; d0 += 4) {
      const float4 w0 = *(const float4*)&wxT[(d0 + 0) * WPAD + e0];
      const float4 w1 = *(const float4*)&wxT[(d0 + 1) * WPAD + e0];
      const float4 w2 = *(const float4*)&wxT[(d0 + 2) * WPAD + e0];
      const float4 w3 = *(const float4*)&wxT[(d0 + 3) * WPAD + e0];
      #pragma unroll
      for (int ri = 0; ri < 4; ++ri) {
        const float4 xv = *(const float4*)&xt[(rg * 4 + ri) * D + d0];
        fma4(acc[ri], xv.x, w0);
        fma4(acc[ri], xv.y, w1);
        fma4(acc[ri], xv.z, w2);
        fma4(acc[ri], xv.w, w3);
      }
    }

    const float4 b4 = *(const float4*)&bias[e0];
    #pragma unroll
    for (int ri = 0; ri < 4; ++ri) {
      const int r = r0 + rg * 4 + ri;
      if (r < N) {
        float4 o;
        o.x = acc[ri].x + b4.x;
        o.y = acc[ri].y + b4.y;
        o.z = acc[ri].z + b4.z;
        o.w = acc[ri].w + b4.w;
        *(float4*)&out[(size_t)r * D + e0] = o;
      }
    }
    __syncthreads();
  }
}

// Fused: n_s matmul + h + leaky + scores + softmax + weighted sum.
// Reads base[n] from `out` (written by base_kernel), overwrites out[n] with the result.
__global__ __launch_bounds__(512) void gnn_kernel(
    const float* __restrict__ x_nb, const float* __restrict__ weight,
    const float* __restrict__ Wn, const float* __restrict__ Ww,
    const float* __restrict__ Wl, float* __restrict__ out, int N)
{
  __shared__ float wnT[D * WPAD];      // 67584 B: wnT[d*WPAD+e] = Wn[e,d]
  __shared__ float xnb[2][KN][D];      // 32768 B
  __shared__ float basel[2][D];
  __shared__ float wwl[D];
  __shared__ float wll[D];
  __shared__ float wgt[2][KN];
  __shared__ float scl[2][KN];
  __shared__ float attnl[2][KN];

  const int tid = threadIdx.x;
  for (int i = tid; i < D * D; i += 512) {
    wnT[(i & (D - 1)) * WPAD + (i >> 7)] = Wn[i];
  }
  if (tid < D) { wwl[tid] = Ww[tid]; wll[tid] = Wl[tid]; }
  __syncthreads();

  const int h = tid >> 8;          // which of the 2 nodes this half-block owns
  const int t = tid & 255;
  const int eg = t & 31, kg = t >> 5;
  const int e0 = eg * 4, k0 = kg * 4;
  const int npairs = N >> 1;

  for (int p = blockIdx.x; p < npairs; p += gridDim.x) {
    const int n0 = p * 2;
    {
      const float4* src = (const float4*)(x_nb + (size_t)n0 * KN * D);
      float4* dst = (float4*)&xnb[0][0][0];
      for (int i = tid; i < 2 * KN * D / 4; i += 512) dst[i] = src[i];
      if (tid < 2 * D) (&basel[0][0])[tid] = out[(size_t)n0 * D + tid];
      if (tid < 2 * KN) (&wgt[0][0])[tid] = weight[(size_t)n0 * KN + tid];
    }
    __syncthreads();

    // n_s: acc[ki][e0..e0+3] = sum_d x_nb[n0+h, k0+ki, d] * Wn[e, d]
    float4 acc[4];
    #pragma unroll
    for (int ki = 0; ki < 4; ++ki) { acc[ki].x = acc[ki].y = acc[ki].z = acc[ki].w = 0.0f; }

    for (int d0 = 0; d0 < D; d0 += 4) {
      const float4 w0 = *(const float4*)&wnT[(d0 + 0) * WPAD + e0];
      const float4 w1 = *(const float4*)&wnT[(d0 + 1) * WPAD + e0];
      const float4 w2 = *(const float4*)&wnT[(d0 + 2) * WPAD + e0];
      const float4 w3 = *(const float4*)&wnT[(d0 + 3) * WPAD + e0];
      #pragma unroll
      for (int ki = 0; ki < 4; ++ki) {
        const float4 xv = *(const float4*)&xnb[h][k0 + ki][d0];
        fma4(acc[ki], xv.x, w0);
        fma4(acc[ki], xv.y, w1);
        fma4(acc[ki], xv.z, w2);
        fma4(acc[ki], xv.w, w3);
      }
    }

    // scores: s[k] = sum_e leaky(acc + base[e] + weight[k]*Ww[e]) * Wl[e]   (bl dropped: softmax-invariant)
    const float4 b4  = *(const float4*)&basel[h][e0];
    const float4 ww4 = *(const float4*)&wwl[e0];
    const float4 wl4 = *(const float4*)&wll[e0];
    #pragma unroll
    for (int ki = 0; ki < 4; ++ki) {
      const float wk = wgt[h][k0 + ki];
      float4 hv;
      hv.x = acc[ki].x + b4.x + wk * ww4.x;
      hv.y = acc[ki].y + b4.y + wk * ww4.y;
      hv.z = acc[ki].z + b4.z + wk * ww4.z;
      hv.w = acc[ki].w + b4.w + wk * ww4.w;
      hv.x = fmaxf(hv.x, 0.1f * hv.x);   // LeakyReLU(0.1)
      hv.y = fmaxf(hv.y, 0.1f * hv.y);
      hv.z = fmaxf(hv.z, 0.1f * hv.z);
      hv.w = fmaxf(hv.w, 0.1f * hv.w);
      float s = hv.x * wl4.x + hv.y * wl4.y + hv.z * wl4.z + hv.w * wl4.w;
      #pragma unroll
      for (int m = 16; m >= 1; m >>= 1) s += __shfl_xor(s, m);
      if (eg == 0) scl[h][k0 + ki] = s;
    }
    __syncthreads();

    // softmax over K=32 (one wave handles both halves)
    if (tid < 64) {
      const int hh = tid >> 5, k = tid & 31;
      const float s = scl[hh][k];
      float mx = s;
      #pragma unroll
      for (int m = 16; m >= 1; m >>= 1) mx = fmaxf(mx, __shfl_xor(mx, m));
      const float pe = __expf(s - mx);
      float sum = pe;
      #pragma unroll
      for (int m = 16; m >= 1; m >>= 1) sum += __shfl_xor(sum, m);
      attnl[hh][k] = pe / sum;
    }
    __syncthreads();

    // out[n,d] = sum_k attn[k] * x_nb[n,k,d]
    if (t < D) {
      float o = 0.0f;
      #pragma unroll
      for (int k = 0; k < KN; ++k) o = fmaf(attnl[h][k], xnb[h][k][t], o);
      out[(size_t)(n0 + h) * D + t] = o;
    }
    __syncthreads();  // protect xnb/scl before next iteration's staging
  }
}

extern "C" void kernel_launch(void* const* d_in, const int* in_sizes, int n_in,
                              void* d_out, int out_size, void* d_ws, size_t ws_size,
                              hipStream_t stream) {
  const float* x      = (const float*)d_in[0];
  const float* x_nb   = (const float*)d_in[1];
  const float* weight = (const float*)d_in[2];
  const float* Wx     = (const float*)d_in[3];
  const float* bx     = (const float*)d_in[4];
  const float* Wn     = (const float*)d_in[5];
  const float* bn     = (const float*)d_in[6];
  const float* Ww     = (const float*)d_in[7];
  const float* bw     = (const float*)d_in[8];
  const float* Wl     = (const float*)d_in[9];
  float* out = (float*)d_out;
  const int N = in_sizes[0] / D;  // 50000

  base_kernel<<<dim3(1024), dim3(256), 0, stream>>>(x, Wx, bx, bn, bw, out, N);
  gnn_kernel<<<dim3(1024), dim3(512), 0, stream>>>(x_nb, weight, Wn, Ww, Wl, out, N);
}

// Round 2
// 257.259 us; speedup vs baseline: 4.5105x; 4.5105x over previous
//
#include <hip/hip_runtime.h>

#define D 128
#define KN 32

typedef __bf16 bf16x8 __attribute__((ext_vector_type(8)));
typedef float f32x4 __attribute__((ext_vector_type(4)));

// --- f32 -> bf16 (RNE) packing helpers -------------------------------------
__device__ __forceinline__ unsigned bfpack2(float a, float b) {
  unsigned ua = __float_as_uint(a), ub = __float_as_uint(b);
  ua += 0x7FFFu + ((ua >> 16) & 1u);
  ub += 0x7FFFu + ((ub >> 16) & 1u);
  return (ua >> 16) | (ub & 0xFFFF0000u);
}
__device__ __forceinline__ uint4 pack8(const float4& a, const float4& b) {
  uint4 r;
  r.x = bfpack2(a.x, a.y); r.y = bfpack2(a.z, a.w);
  r.z = bfpack2(b.x, b.y); r.w = bfpack2(b.z, b.w);
  return r;
}

// Stage 128 rows x 128 cols f32 -> bf16 into LDS as XOR-swizzled 16B chunks.
// Chunk layout: buf[row*16 + (slot ^ (row & 7))] holds bf16 of cols slot*8..slot*8+7.
// Requires blockDim.x == 512. Rows >= nrows are zero-filled.
__device__ __forceinline__ void stage128(const float* __restrict__ src, int nrows,
                                         uint4* buf, int tid) {
  float4 v[4][2];
  #pragma unroll
  for (int i = 0; i < 4; ++i) {
    const int c = i * 512 + tid;
    const int row = c >> 4, slot = c & 15;
    if (row < nrows) {
      const float4* p = (const float4*)(src + (size_t)row * D + slot * 8);
      v[i][0] = p[0]; v[i][1] = p[1];
    } else {
      v[i][0] = make_float4(0.f, 0.f, 0.f, 0.f);
      v[i][1] = make_float4(0.f, 0.f, 0.f, 0.f);
    }
  }
  #pragma unroll
  for (int i = 0; i < 4; ++i) {
    const int c = i * 512 + tid;
    const int row = c >> 4, slot = c & 15;
    buf[row * 16 + (slot ^ (row & 7))] = pack8(v[i][0], v[i][1]);
  }
}

// One 128x128x128 bf16 MFMA tile: wave (rq, ch) computes rows [32rq,32rq+32) x
// cols [64ch, 64ch+64). acc[rt][ct]: rt = 16-row subtile, ct = 16-col subtile.
// A-frag: lane holds A[row=li][k=g*8+j]; B-frag: B[k=g*8+j][col=li].
__device__ __forceinline__ void mfma128(const uint4* Abuf, const uint4* Bbuf,
                                        int rq, int ch, int li, int g,
                                        f32x4 acc[2][4]) {
  #pragma unroll
  for (int kb = 0; kb < 4; ++kb) {
    const int slot = kb * 4 + g;
    const int r0 = rq * 32 + li, r1 = r0 + 16;
    const bf16x8 a0 = __builtin_bit_cast(bf16x8, Abuf[r0 * 16 + (slot ^ (r0 & 7))]);
    const bf16x8 a1 = __builtin_bit_cast(bf16x8, Abuf[r1 * 16 + (slot ^ (r1 & 7))]);
    #pragma unroll
    for (int ct = 0; ct < 4; ++ct) {
      const int e = ch * 64 + ct * 16 + li;
      const bf16x8 b = __builtin_bit_cast(bf16x8, Bbuf[e * 16 + (slot ^ (e & 7))]);
      acc[0][ct] = __builtin_amdgcn_mfma_f32_16x16x32_bf16(a0, b, acc[0][ct], 0, 0, 0);
      acc[1][ct] = __builtin_amdgcn_mfma_f32_16x16x32_bf16(a1, b, acc[1][ct], 0, 0, 0);
    }
  }
}

// base[r,e] = sum_d x[r,d]*Wx[e,d] + bx[e]+bn[e]+bw[e]  -> d_out
__global__ __launch_bounds__(512, 4) void base_mfma(
    const float* __restrict__ x, const float* __restrict__ Wx,
    const float* __restrict__ bx, const float* __restrict__ bn,
    const float* __restrict__ bw, float* __restrict__ out, int N)
{
  __shared__ uint4 Bb[2048];   // Wx bf16 chunks (B[k=d][n=e] = Wx[e][d])
  __shared__ uint4 Ab[2048];   // x rows bf16 chunks
  __shared__ float bvec[D];
  const int tid = threadIdx.x;

  stage128(Wx, 128, Bb, tid);
  if (tid < D) bvec[tid] = bx[tid] + bn[tid] + bw[tid];

  const int lane = tid & 63, li = lane & 15, g = lane >> 4;
  const int wv = tid >> 6, rq = wv >> 1, ch = wv & 1;
  const int ntiles = (N + 127) >> 7;

  for (int t = blockIdx.x; t < ntiles; t += gridDim.x) {
    const int r0t = t << 7;
    __syncthreads();
    stage128(x + (size_t)r0t * D, N - r0t, Ab, tid);
    __syncthreads();

    f32x4 acc[2][4];
    #pragma unroll
    for (int i = 0; i < 2; ++i)
      #pragma unroll
      for (int j = 0; j < 4; ++j) acc[i][j] = (f32x4){0.f, 0.f, 0.f, 0.f};

    mfma128(Ab, Bb, rq, ch, li, g, acc);

    #pragma unroll
    for (int rt = 0; rt < 2; ++rt) {
      #pragma unroll
      for (int reg = 0; reg < 4; ++reg) {
        const int r = r0t + rq * 32 + rt * 16 + 4 * g + reg;
        if (r < N) {
          #pragma unroll
          for (int ct = 0; ct < 4; ++ct) {
            const int e = ch * 64 + ct * 16 + li;
            out[(size_t)r * D + e] = acc[rt][ct][reg] + bvec[e];
          }
        }
      }
    }
  }
}

// Fused: n_s MFMA + h + leaky + scores + softmax + exact-f32 weighted sum.
// Reads base[n] from `out` (written by base_mfma), overwrites out[n].
__global__ __launch_bounds__(512, 4) void gnn_mfma(
    const float* __restrict__ x_nb, const float* __restrict__ weight,
    const float* __restrict__ Wn, const float* __restrict__ Ww,
    const float* __restrict__ Wl, float* __restrict__ out, int N)
{
  __shared__ uint4 Bb[2048];       // Wn bf16 chunks
  __shared__ uint4 Ab[2048];       // x_nb tile (4 nodes x 32 nbrs) bf16 chunks
  __shared__ float basel[4 * D];
  __shared__ float wwl[D], wll[D];
  __shared__ float wgt[4 * KN];
  __shared__ float spart[2][4][KN];
  __shared__ float attnl[4 * KN];
  const int tid = threadIdx.x;

  stage128(Wn, 128, Bb, tid);
  if (tid < D) { wwl[tid] = Ww[tid]; wll[tid] = Wl[tid]; }

  const int lane = tid & 63, li = lane & 15, g = lane >> 4;
  const int wv = tid >> 6, rq = wv >> 1, ch = wv & 1;   // node = rq, e-half = ch
  const int ntiles = N >> 2;                             // N % 4 == 0 (50000)

  for (int t = blockIdx.x; t < ntiles; t += gridDim.x) {
    const int n0 = t * 4;
    __syncthreads();  // protect LDS from previous iteration's consumers
    stage128(x_nb + (size_t)n0 * KN * D, 128, Ab, tid);
    basel[tid] = out[(size_t)n0 * D + tid];              // 512 = 4 nodes x 128
    if (tid < 4 * KN) wgt[tid] = weight[(size_t)n0 * KN + tid];
    __syncthreads();

    f32x4 acc[2][4];
    #pragma unroll
    for (int i = 0; i < 2; ++i)
      #pragma unroll
      for (int j = 0; j < 4; ++j) acc[i][j] = (f32x4){0.f, 0.f, 0.f, 0.f};

    mfma128(Ab, Bb, rq, ch, li, g, acc);

    // scores: s[k] = sum_e leaky(n_s + base + w*Ww) * Wl  (bl softmax-invariant)
    float bvv[4], wwv[4], wlv[4];
    #pragma unroll
    for (int ct = 0; ct < 4; ++ct) {
      const int e = ch * 64 + ct * 16 + li;
      bvv[ct] = basel[rq * D + e];
      wwv[ct] = wwl[e];
      wlv[ct] = wll[e];
    }
    #pragma unroll
    for (int rt = 0; rt < 2; ++rt) {
      #pragma unroll
      for (int reg = 0; reg < 4; ++reg) {
        const int k = rt * 16 + 4 * g + reg;
        const float wk = wgt[rq * KN + k];
        float p = 0.f;
        #pragma unroll
        for (int ct = 0; ct < 4; ++ct) {
          float h = acc[rt][ct][reg] + bvv[ct] + wk * wwv[ct];
          h = fmaxf(h, 0.1f * h);            // LeakyReLU(0.1)
          p = fmaf(h, wlv[ct], p);
        }
        p += __shfl_xor(p, 1);
        p += __shfl_xor(p, 2);
        p += __shfl_xor(p, 4);
        p += __shfl_xor(p, 8);
        if (li == 0) spart[ch][rq][k] = p;
      }
    }
    __syncthreads();

    // softmax over K=32 per node (waves 0-1; k-groups of 32 lanes)
    if (tid < 128) {
      const int node = tid >> 5, k = tid & 31;
      const float s = spart[0][node][k] + spart[1][node][k];
      float mx = s;
      #pragma unroll
      for (int m = 16; m >= 1; m >>= 1) mx = fmaxf(mx, __shfl_xor(mx, m));
      const float pe = __expf(s - mx);
      float sum = pe;
      #pragma unroll
      for (int m = 16; m >= 1; m >>= 1) sum += __shfl_xor(sum, m);
      attnl[node * KN + k] = pe / sum;
    }
    __syncthreads();

    // out[n,d] = sum_k attn[k] * x_nb[n,k,d]  (exact f32 re-read; L2-hot)
    {
      const int node = tid >> 7, dd = tid & 127;
      const float* xg = x_nb + (size_t)(n0 + node) * KN * D + dd;
      float o = 0.f;
      #pragma unroll
      for (int k = 0; k < KN; ++k) o = fmaf(attnl[node * KN + k], xg[(size_t)k * D], o);
      out[(size_t)(n0 + node) * D + dd] = o;
    }
  }
}

extern "C" void kernel_launch(void* const* d_in, const int* in_sizes, int n_in,
                              void* d_out, int out_size, void* d_ws, size_t ws_size,
                              hipStream_t stream) {
  const float* x      = (const float*)d_in[0];
  const float* x_nb   = (const float*)d_in[1];
  const float* weight = (const float*)d_in[2];
  const float* Wx     = (const float*)d_in[3];
  const float* bx     = (const float*)d_in[4];
  const float* Wn     = (const float*)d_in[5];
  const float* bn     = (const float*)d_in[6];
  const float* Ww     = (const float*)d_in[7];
  const float* bw     = (const float*)d_in[8];
  const float* Wl     = (const float*)d_in[9];
  float* out = (float*)d_out;
  const int N = in_sizes[0] / D;  // 50000

  base_mfma<<<dim3(391), dim3(512), 0, stream>>>(x, Wx, bx, bn, bw, out, N);
  gnn_mfma<<<dim3(512), dim3(512), 0, stream>>>(x_nb, weight, Wn, Ww, Wl, out, N);
}